// Round 5
// baseline (212.328 us; speedup 1.0000x reference)
//
#include <hip/hip_runtime.h>
#include <math.h>

#define EPSF 1e-6f
#define MAX_ACOSH_ARGF 1e6f
#define MAX_DISTF 50.0f
#define TINYF 1e-15f

constexpr int QSZ  = 16 * 512 * 33;      // Q floats (row-major [bh][t][33])
constexpr int KTSZ = 16 * 9 * 512 * 4;   // K/V transposed-f4 floats [bh][j][t][4]
constexpr int ZTSZ = 1024 * 264;

__device__ __forceinline__ float facosh(float a) {
    // a >= 1+EPS guaranteed by clamp; (a-1)(a+1) avoids a*a-1 cancellation
    return __logf(a + sqrtf((a - 1.0f) * (a + 1.0f)));
}
__device__ __forceinline__ float bcast(float x) {
    return __int_as_float(__builtin_amdgcn_readfirstlane(__float_as_int(x)));
}

// ---------------- Kernel 1: QKV GEMM (LDS-free wave tiles) + lift -------------
// wave-tile: 8 bt-rows x 128 cols; A(x) rows via wave-uniform s_loads; B(W)
// streamed from L2 (float2/lane). Lift fused; K/V written transposed-f4.
__global__ __launch_bounds__(256) void qkv_kernel(
    const float* __restrict__ x,
    const float* __restrict__ Wq, const float* __restrict__ bq,
    const float* __restrict__ Wk, const float* __restrict__ bk,
    const float* __restrict__ Wv, const float* __restrict__ bv,
    float* __restrict__ Q, float* __restrict__ KT, float* __restrict__ VT)
{
    const int tid  = threadIdx.x;
    const int wiu  = __builtin_amdgcn_readfirstlane(tid >> 6);
    const int lane = tid & 63;
    const int gw   = blockIdx.x * 4 + wiu;     // 0..767
    const int ct   = gw % 6;                   // col tile (tensor*2 + half)
    const int mt   = gw / 6;                   // 0..127
    const int m0   = mt * 8;
    const int tsel = ct >> 1;
    const int n0   = (ct & 1) * 128;
    const float* W    = (tsel == 0) ? Wq : (tsel == 1) ? Wk : Wv;
    const float* bias = (tsel == 0) ? bq : (tsel == 1) ? bk : bv;
    const int c0 = n0 + lane * 2;

    float acc[8][2];
    {
        const float b0 = bias[c0], b1 = bias[c0 + 1];
        #pragma unroll
        for (int r = 0; r < 8; ++r) { acc[r][0] = b0; acc[r][1] = b1; }
    }

    for (int kb = 0; kb < 512; kb += 8) {
        float xa[8][8];                         // wave-uniform -> scalar regs
        #pragma unroll
        for (int r = 0; r < 8; ++r) {
            const float4 t0 = *(const float4*)(x + (m0 + r) * 512 + kb);
            const float4 t1 = *(const float4*)(x + (m0 + r) * 512 + kb + 4);
            xa[r][0] = t0.x; xa[r][1] = t0.y; xa[r][2] = t0.z; xa[r][3] = t0.w;
            xa[r][4] = t1.x; xa[r][5] = t1.y; xa[r][6] = t1.z; xa[r][7] = t1.w;
        }
        #pragma unroll
        for (int k8 = 0; k8 < 8; ++k8) {
            const float2 bv2 = *(const float2*)(W + (kb + k8) * 256 + c0);
            #pragma unroll
            for (int r = 0; r < 8; ++r) {
                acc[r][0] = fmaf(xa[r][k8], bv2.x, acc[r][0]);
                acc[r][1] = fmaf(xa[r][k8], bv2.y, acc[r][1]);
            }
        }
    }

    // fused lift: each 16-lane subgroup = one head's 32 cols
    const int cin = (lane & 15) * 2;            // in-head col
    const int h   = (n0 + lane * 2) >> 5;
    #pragma unroll
    for (int r = 0; r < 8; ++r) {
        const float e0 = acc[r][0], e1 = acc[r][1];
        float n2 = fmaf(e0, e0, e1 * e1);
        #pragma unroll
        for (int msk = 1; msk < 16; msk <<= 1) n2 += __shfl_xor(n2, msk, 64);
        n2 = fmaxf(n2, TINYF);
        const float vn = sqrtf(n2);
        const float ch = coshf(vn);
        const float sh = sinhf(vn) / fmaxf(vn, TINYF);
        const float xx = fmaf(sh * sh, n2, -ch * ch);
        const float scale = sqrtf(fmaxf(fabsf(xx), TINYF));
        const float fs = sh / scale;
        const int bt = m0 + r, b = bt >> 9, t = bt & 511;
        const int bh = b * 8 + h;
        if (tsel == 0) {
            float* qp = Q + (bh * 512 + t) * 33;
            qp[1 + cin] = fs * e0;
            qp[2 + cin] = fs * e1;
            if (cin == 0) qp[0] = fabsf(ch / scale);
        } else {
            float* P = ((tsel == 1) ? KT : VT) + bh * 18432;   // [9][512][4]
            const int aa = 1 + cin, ab = 2 + cin;
            P[(aa >> 2) * 2048 + t * 4 + (aa & 3)] = fs * e0;
            P[(ab >> 2) * 2048 + t * 4 + (ab & 3)] = fs * e1;
            if (cin == 0) P[t * 4] = fabsf(ch / scale);
            if (cin == 30) {                    // zero pad comps (a=33..35)
                P[8 * 2048 + t * 4 + 1] = 0.0f;
                P[8 * 2048 + t * 4 + 2] = 0.0f;
                P[8 * 2048 + t * 4 + 3] = 0.0f;
            }
        }
    }
}

// ---------------- Kernel 2: attention + Karcher step + log-map ----------------
// 1024 blocks = 16 bh x 64 q-tiles(8 q). 256 thr = 4 waves; wave = 2 q (SGPRs).
// lane = k: each lane owns one K/V row per 64-row chunk, read as 9 contiguous
// b128 from LDS (conflict-free). Double-buffered chunks, 1 barrier each.
__global__ __launch_bounds__(256) void attn_kernel(
    const float* __restrict__ Q, const float* __restrict__ KT,
    const float* __restrict__ VT, float* __restrict__ ZT)
{
    __shared__ __align__(16) float4 sm4[2304 + 67];   // 2 x (K 576 | V 576) + Q rows
    float* Qs = (float*)(sm4 + 2304);

    const int blk = blockIdx.x;
    const int bh  = blk >> 6;
    const int q0  = (blk & 63) * 8;
    const int tid = threadIdx.x;
    const int wiu = __builtin_amdgcn_readfirstlane(tid >> 6);
    const int k   = tid & 63;

    const float4* Ksrc = (const float4*)KT + bh * 4608;
    const float4* Vsrc = (const float4*)VT + bh * 4608;
    const float*  Qg   = Q + (bh * 512 + q0) * 33;

    for (int i = tid; i < 264; i += 256) Qs[i] = Qg[i];
    for (int idx = tid; idx < 1152; idx += 256) {
        const int mtx = idx >= 576 ? 1 : 0;
        const int rem = idx - mtx * 576;
        sm4[idx] = (mtx ? Vsrc : Ksrc)[(rem >> 6) * 512 + (rem & 63)];
    }
    __syncthreads();

    // 2 q rows per wave, negated-spatial, padded to 36, in SGPRs
    float qn0[36], qn1[36];
    {
        const int r0 = 2 * wiu, r1 = r0 + 1;
        #pragma unroll
        for (int a = 0; a < 36; ++a) {
            float v0 = (a < 33) ? Qs[r0 * 33 + a] : 0.0f;
            float v1 = (a < 33) ? Qs[r1 * 33 + a] : 0.0f;
            if (a >= 1) { v0 = -v0; v1 = -v1; }
            qn0[a] = bcast(v0); qn1[a] = bcast(v1);
        }
    }

    float mv0 = -3.0e38f, lv0 = 0.0f, sa0 = 0.0f;
    float mv1 = -3.0e38f, lv1 = 0.0f, sa1 = 0.0f;
    float ac0[33], ac1[33];
    #pragma unroll
    for (int a = 0; a < 33; ++a) { ac0[a] = 0.0f; ac1[a] = 0.0f; }

    for (int c = 0; c < 8; ++c) {
        if (c < 7) {                    // stage next chunk into other buffer
            const int cn = c + 1;
            const int bb = (cn & 1) * 1152;
            for (int idx = tid; idx < 1152; idx += 256) {
                const int mtx = idx >= 576 ? 1 : 0;
                const int rem = idx - mtx * 576;
                sm4[bb + idx] = (mtx ? Vsrc : Ksrc)[(rem >> 6) * 512 + cn * 64 + (rem & 63)];
            }
        }
        const float4* bK = sm4 + (c & 1) * 1152;
        const float4* bV = bK + 576;

        float kf[36];
        #pragma unroll
        for (int j = 0; j < 9; ++j) {
            const float4 t = bK[j * 64 + k];
            kf[4*j] = t.x; kf[4*j+1] = t.y; kf[4*j+2] = t.z; kf[4*j+3] = t.w;
        }
        float p00=0.f,p01=0.f,p02=0.f,p03=0.f, p10=0.f,p11=0.f,p12=0.f,p13=0.f;
        #pragma unroll
        for (int j = 0; j < 9; ++j) {
            p00 = fmaf(qn0[4*j],   kf[4*j],   p00);
            p01 = fmaf(qn0[4*j+1], kf[4*j+1], p01);
            p02 = fmaf(qn0[4*j+2], kf[4*j+2], p02);
            p03 = fmaf(qn0[4*j+3], kf[4*j+3], p03);
            p10 = fmaf(qn1[4*j],   kf[4*j],   p10);
            p11 = fmaf(qn1[4*j+1], kf[4*j+1], p11);
            p12 = fmaf(qn1[4*j+2], kf[4*j+2], p12);
            p13 = fmaf(qn1[4*j+3], kf[4*j+3], p13);
        }
        const float al10 = (p00 + p01) + (p02 + p03);
        const float al11 = (p10 + p11) + (p12 + p13);

        float vf[36];
        #pragma unroll
        for (int j = 0; j < 9; ++j) {
            const float4 t = bV[j * 64 + k];
            vf[4*j] = t.x; vf[4*j+1] = t.y; vf[4*j+2] = t.z; vf[4*j+3] = t.w;
        }
        float r00=0.f,r01=0.f,r02=0.f,r03=0.f, r10=0.f,r11=0.f,r12=0.f,r13=0.f;
        #pragma unroll
        for (int j = 0; j < 9; ++j) {
            r00 = fmaf(qn0[4*j],   vf[4*j],   r00);
            r01 = fmaf(qn0[4*j+1], vf[4*j+1], r01);
            r02 = fmaf(qn0[4*j+2], vf[4*j+2], r02);
            r03 = fmaf(qn0[4*j+3], vf[4*j+3], r03);
            r10 = fmaf(qn1[4*j],   vf[4*j],   r10);
            r11 = fmaf(qn1[4*j+1], vf[4*j+1], r11);
            r12 = fmaf(qn1[4*j+2], vf[4*j+2], r12);
            r13 = fmaf(qn1[4*j+3], vf[4*j+3], r13);
        }
        const float al20 = (r00 + r01) + (r02 + r03);
        const float al21 = (r10 + r11) + (r12 + r13);

        {   // q0 update
            const float a1c = fminf(fmaxf(al10, 1.0f + EPSF), MAX_ACOSH_ARGF);
            const float d1  = fminf(facosh(a1c), MAX_DISTF);
            const float sN  = -d1 * d1;
            const float a2c = fminf(fmaxf(al20, 1.0f + EPSF), MAX_ACOSH_ARGF);
            const float d2  = facosh(a2c);
            if (sN > mv0) {
                const float cr = __expf(mv0 - sN);
                lv0 *= cr; sa0 *= cr;
                #pragma unroll
                for (int a = 0; a < 33; ++a) ac0[a] *= cr;
                mv0 = sN;
            }
            const float e = __expf(sN - mv0);
            lv0 += e;
            const float w = e * d2;
            sa0 = fmaf(w, a2c, sa0);
            #pragma unroll
            for (int a = 0; a < 33; ++a) ac0[a] = fmaf(w, vf[a], ac0[a]);
        }
        {   // q1 update
            const float a1c = fminf(fmaxf(al11, 1.0f + EPSF), MAX_ACOSH_ARGF);
            const float d1  = fminf(facosh(a1c), MAX_DISTF);
            const float sN  = -d1 * d1;
            const float a2c = fminf(fmaxf(al21, 1.0f + EPSF), MAX_ACOSH_ARGF);
            const float d2  = facosh(a2c);
            if (sN > mv1) {
                const float cr = __expf(mv1 - sN);
                lv1 *= cr; sa1 *= cr;
                #pragma unroll
                for (int a = 0; a < 33; ++a) ac1[a] *= cr;
                mv1 = sN;
            }
            const float e = __expf(sN - mv1);
            lv1 += e;
            const float w = e * d2;
            sa1 = fmaf(w, a2c, sa1);
            #pragma unroll
            for (int a = 0; a < 33; ++a) ac1[a] = fmaf(w, vf[a], ac1[a]);
        }
        __syncthreads();
    }

    // ---- 64-lane merge: max, scale once, butterfly sums ----
    float M0 = mv0, M1 = mv1;
    #pragma unroll
    for (int msk = 1; msk < 64; msk <<= 1) {
        M0 = fmaxf(M0, __shfl_xor(M0, msk, 64));
        M1 = fmaxf(M1, __shfl_xor(M1, msk, 64));
    }
    const float cl0 = __expf(mv0 - M0), cl1 = __expf(mv1 - M1);
    float lw0 = lv0 * cl0, sw0 = sa0 * cl0;
    float lw1 = lv1 * cl1, sw1 = sa1 * cl1;
    #pragma unroll
    for (int msk = 1; msk < 64; msk <<= 1) {
        lw0 += __shfl_xor(lw0, msk, 64);
        sw0 += __shfl_xor(sw0, msk, 64);
        lw1 += __shfl_xor(lw1, msk, 64);
        sw1 += __shfl_xor(sw1, msk, 64);
    }
    #pragma unroll
    for (int a = 0; a < 33; ++a) {
        float v0 = ac0[a] * cl0, v1 = ac1[a] * cl1;
        #pragma unroll
        for (int msk = 1; msk < 64; msk <<= 1) {
            v0 += __shfl_xor(v0, msk, 64);
            v1 += __shfl_xor(v1, msk, 64);
        }
        ac0[a] = v0; ac1[a] = v1;
    }

    const int b = bh >> 3, h = bh & 7;
    const float un_c = sqrtf(TINYF);

    #pragma unroll
    for (int q = 0; q < 2; ++q) {
        float (&ac)[33] = q ? ac1 : ac0;
        float (&qn)[36] = q ? qn1 : qn0;
        const float lw = q ? lw1 : lw0;
        const float sw = q ? sw1 : sw0;
        const float inv_un = (1.0f / (q ? lw1 : lw0)) / un_c;
        // fold scalar Q-side accumulator; Qtrue = (qn[0], -qn[a>=1])
        ac[0] = fmaf(sw, qn[0], ac[0]) * inv_un;
        #pragma unroll
        for (int a = 1; a < 33; ++a) ac[a] = fmaf(-sw, qn[a], ac[a]) * inv_un;

        float mk = -ac[0] * ac[0];
        #pragma unroll
        for (int a = 1; a < 33; ++a) mk = fmaf(ac[a], ac[a], mk);
        const float snorm = sqrtf(fmaxf(mk, TINYF));
        const float fac   = fminf(snorm, 20.0f) / (snorm + 1e-9f);
        #pragma unroll
        for (int a = 0; a < 33; ++a) ac[a] *= fac;

        float mk2 = -ac[0] * ac[0];
        #pragma unroll
        for (int a = 1; a < 33; ++a) mk2 = fmaf(ac[a], ac[a], mk2);
        const float vn  = sqrtf(fmaxf(mk2, TINYF));
        const float ch  = coshf(vn);
        const float shr = sinhf(vn) / fmaxf(vn, TINYF);
        ac[0] = fmaf(ch, qn[0], shr * ac[0]);
        #pragma unroll
        for (int a = 1; a < 33; ++a) ac[a] = fmaf(-ch, qn[a], shr * ac[a]);  // y

        float xx = -ac[0] * ac[0];
        #pragma unroll
        for (int a = 1; a < 33; ++a) xx = fmaf(ac[a], ac[a], xx);
        const float scale = sqrtf(fmaxf(fabsf(xx), TINYF));

        const float Y0  = fabsf(ac[0] / scale);
        const float al3 = fminf(fmaxf(Y0, 1.0f + EPSF), MAX_ACOSH_ARGF);
        const float d3  = acoshf(al3);
        const float f3  = d3 / un_c;

        if (k == q) {
            const int qi = q0 + 2 * wiu + q;
            float* zp = ZT + (b * 512 + qi) * 264 + h * 33;
            zp[0] = f3 * (Y0 + al3);
            const float fsc = f3 / scale;
            #pragma unroll
            for (int a = 1; a < 33; ++a) zp[a] = fsc * ac[a];
        }
        (void)lw;
    }
}

// ---------------- Kernel 3: Z = Z_tan @ Wo + bo (LDS-free wave tiles) ---------
__global__ __launch_bounds__(256) void out_kernel(
    const float* __restrict__ ZT, const float* __restrict__ Wo,
    const float* __restrict__ bo, float* __restrict__ out)
{
    const int tid  = threadIdx.x;
    const int wiu  = __builtin_amdgcn_readfirstlane(tid >> 6);
    const int lane = tid & 63;
    const int gw   = blockIdx.x * 4 + wiu;    // 0..1023
    const int mt   = gw >> 2;
    const int n0   = (gw & 3) * 128;
    const int m0   = mt * 4;
    const int c0   = n0 + lane * 2;

    float acc[4][2];
    {
        const float b0 = bo[c0], b1 = bo[c0 + 1];
        #pragma unroll
        for (int r = 0; r < 4; ++r) { acc[r][0] = b0; acc[r][1] = b1; }
    }

    for (int kb = 0; kb < 264; kb += 8) {
        float za[4][8];
        #pragma unroll
        for (int r = 0; r < 4; ++r) {
            const float4 t0 = *(const float4*)(ZT + (m0 + r) * 264 + kb);
            const float4 t1 = *(const float4*)(ZT + (m0 + r) * 264 + kb + 4);
            za[r][0] = t0.x; za[r][1] = t0.y; za[r][2] = t0.z; za[r][3] = t0.w;
            za[r][4] = t1.x; za[r][5] = t1.y; za[r][6] = t1.z; za[r][7] = t1.w;
        }
        #pragma unroll
        for (int k8 = 0; k8 < 8; ++k8) {
            const float2 bv2 = *(const float2*)(Wo + (kb + k8) * 512 + c0);
            #pragma unroll
            for (int r = 0; r < 4; ++r) {
                acc[r][0] = fmaf(za[r][k8], bv2.x, acc[r][0]);
                acc[r][1] = fmaf(za[r][k8], bv2.y, acc[r][1]);
            }
        }
    }
    #pragma unroll
    for (int r = 0; r < 4; ++r)
        *(float2*)(out + (m0 + r) * 512 + c0) = make_float2(acc[r][0], acc[r][1]);
}

extern "C" void kernel_launch(void* const* d_in, const int* in_sizes, int n_in,
                              void* d_out, int out_size, void* d_ws, size_t ws_size,
                              hipStream_t stream) {
    const float* x  = (const float*)d_in[0];
    const float* Wq = (const float*)d_in[1];
    const float* bq = (const float*)d_in[2];
    const float* Wk = (const float*)d_in[3];
    const float* bk = (const float*)d_in[4];
    const float* Wv = (const float*)d_in[5];
    const float* bv = (const float*)d_in[6];
    const float* Wo = (const float*)d_in[7];
    const float* bo = (const float*)d_in[8];
    float* out = (float*)d_out;
    float* ws  = (float*)d_ws;

    float* Q   = ws;
    float* KT  = ws + QSZ;
    float* VT  = ws + QSZ + KTSZ;
    float* ZTp = ws + QSZ + 2 * KTSZ;

    qkv_kernel<<<192, 256, 0, stream>>>(x, Wq, bq, Wk, bk, Wv, bv, Q, KT, VT);
    attn_kernel<<<1024, 256, 0, stream>>>(Q, KT, VT, ZTp);
    out_kernel<<<256, 256, 0, stream>>>(ZTp, Wo, bo, out);
}

// Round 6
// 171.666 us; speedup vs baseline: 1.2369x; 1.2369x over previous
//
#include <hip/hip_runtime.h>
#include <math.h>

#define EPSF 1e-6f
#define MAX_ACOSH_ARGF 1e6f
#define MAX_DISTF 50.0f
#define TINYF 1e-15f

typedef float f4v __attribute__((ext_vector_type(4)));
typedef float f2v __attribute__((ext_vector_type(2)));

constexpr int QPSZ = 16 * 512 * 36;      // Q padded rows [bh][t][36]
constexpr int KTSZ = 16 * 9 * 512 * 4;   // K/V transposed-f4 [bh][j][t][4]
constexpr int ZTSZ = 1024 * 264;

__device__ __forceinline__ float facosh(float a) {
    // a >= 1+EPS guaranteed by clamp; (a-1)(a+1) avoids a*a-1 cancellation
    return __logf(a + sqrtf((a - 1.0f) * (a + 1.0f)));
}

// ---------------- Kernel 1: QKV GEMM (LDS-free, reg-dbuf) + lift --------------
// 1536 waves: wave = 4 bt-rows x 128 cols. A via same-address vector f4 loads
// (HW-merged), B coalesced f2/lane. Lift fused; K/V written transposed-f4.
__global__ __launch_bounds__(64) void qkv_kernel(
    const float* __restrict__ x,
    const float* __restrict__ Wq, const float* __restrict__ bq,
    const float* __restrict__ Wk, const float* __restrict__ bk,
    const float* __restrict__ Wv, const float* __restrict__ bv,
    float* __restrict__ Qp, float* __restrict__ KT, float* __restrict__ VT)
{
    const int lane = threadIdx.x;
    const int gw   = blockIdx.x;               // 0..1535
    const int ct   = gw % 6;
    const int mt   = gw / 6;                   // 0..255
    const int m0   = mt * 4;
    const int tsel = ct >> 1;
    const int n0   = (ct & 1) * 128;
    const float* W    = (tsel == 0) ? Wq : (tsel == 1) ? Wk : Wv;
    const float* bias = (tsel == 0) ? bq : (tsel == 1) ? bk : bv;
    const int c0 = n0 + lane * 2;
    const float* xb = x + m0 * 512;

    float acc[4][2];
    {
        const float b0 = bias[c0], b1 = bias[c0 + 1];
        #pragma unroll
        for (int r = 0; r < 4; ++r) { acc[r][0] = b0; acc[r][1] = b1; }
    }

    f4v aA[4][2], aB[4][2];
    f2v bA[8], bB[8];

#define LDA_Q(BUF, KB)                                            \
    _Pragma("unroll") for (int r = 0; r < 4; ++r) {               \
        BUF[r][0] = *(const f4v*)(xb + r * 512 + (KB));           \
        BUF[r][1] = *(const f4v*)(xb + r * 512 + (KB) + 4);       \
    }
#define LDB_Q(BUF, KB)                                            \
    _Pragma("unroll") for (int j = 0; j < 8; ++j)                 \
        BUF[j] = *(const f2v*)(W + ((KB) + j) * 256 + c0);
#define STEP_Q(AB, BB)                                            \
    _Pragma("unroll") for (int j = 0; j < 8; ++j) {               \
        _Pragma("unroll") for (int r = 0; r < 4; ++r) {           \
            const float av = AB[r][j >> 2][j & 3];                \
            acc[r][0] = fmaf(av, BB[j][0], acc[r][0]);            \
            acc[r][1] = fmaf(av, BB[j][1], acc[r][1]);            \
        }                                                         \
    }

    LDA_Q(aA, 0) LDB_Q(bA, 0)
    for (int kb = 0; kb < 512; kb += 16) {
        LDA_Q(aB, kb + 8) LDB_Q(bB, kb + 8)
        STEP_Q(aA, bA)
        if (kb + 16 < 512) { LDA_Q(aA, kb + 16) LDB_Q(bA, kb + 16) }
        STEP_Q(aB, bB)
    }

    // fused lift: 16-lane subgroup = one head's 32 cols
    const int h   = c0 >> 5;                   // head within tensor (0..7)
    const int cin = c0 & 31;
    #pragma unroll
    for (int r = 0; r < 4; ++r) {
        const float e0 = acc[r][0], e1 = acc[r][1];
        float n2 = fmaf(e0, e0, e1 * e1);
        #pragma unroll
        for (int msk = 1; msk < 16; msk <<= 1) n2 += __shfl_xor(n2, msk, 64);
        n2 = fmaxf(n2, TINYF);
        const float vn = sqrtf(n2);
        const float ch = coshf(vn);
        const float sh = sinhf(vn) / fmaxf(vn, TINYF);
        const float xx = fmaf(sh * sh, n2, -ch * ch);      // mink(y,y) ~ -1
        const float scale = sqrtf(fmaxf(fabsf(xx), TINYF));
        const float fs = sh / scale;
        const int bt = m0 + r, b = bt >> 9, t = bt & 511;
        const int bh = b * 8 + h;
        if (tsel == 0) {
            float* qp = Qp + (bh * 512 + t) * 36;
            qp[1 + cin] = fs * e0;
            qp[2 + cin] = fs * e1;
            if (cin == 0)  qp[0] = fabsf(ch / scale);
            if (cin == 30) { qp[33] = 0.0f; qp[34] = 0.0f; qp[35] = 0.0f; }
        } else {
            float* P = ((tsel == 1) ? KT : VT) + bh * 18432;   // [9][512][4]
            const int aa = 1 + cin, ab = 2 + cin;
            P[(aa >> 2) * 2048 + t * 4 + (aa & 3)] = fs * e0;
            P[(ab >> 2) * 2048 + t * 4 + (ab & 3)] = fs * e1;
            if (cin == 0)  P[t * 4] = fabsf(ch / scale);
            if (cin == 30) {
                P[8 * 2048 + t * 4 + 1] = 0.0f;
                P[8 * 2048 + t * 4 + 2] = 0.0f;
                P[8 * 2048 + t * 4 + 3] = 0.0f;
            }
        }
    }
}

// ---------------- Kernel 2: attention + Karcher step + log-map ----------------
// 512 blocks x 256 thr = 2048 waves. Wave = 4 q (16-lane groups, 1 q each);
// lane t handles k = t + 16*step. K/V read directly from L2 (coalesced
// transposed layout), no LDS, no barriers. Merge = 4 butterfly levels.
__global__ __launch_bounds__(256) void attn_kernel(
    const float* __restrict__ Qp, const float* __restrict__ KT,
    const float* __restrict__ VT, float* __restrict__ ZT)
{
    const int tid  = threadIdx.x;
    const int blk  = blockIdx.x;          // 0..511
    const int bh   = blk >> 5;
    const int q0   = (blk & 31) * 16;
    const int wid  = tid >> 6;
    const int lane = tid & 63;
    const int g    = lane >> 4;
    const int t    = lane & 15;
    const int qi   = q0 + wid * 4 + g;

    // q row (negated-spatial), padded to 36
    float qn[36];
    {
        const float* qp = Qp + (bh * 512 + qi) * 36;
        #pragma unroll
        for (int j = 0; j < 9; ++j) {
            const f4v v = *(const f4v*)(qp + 4 * j);
            #pragma unroll
            for (int i = 0; i < 4; ++i) {
                const int a = 4 * j + i;
                qn[a] = (a == 0) ? v[i] : -v[i];
            }
        }
    }

    const f4v* K4 = (const f4v*)KT + bh * 4608;
    const f4v* V4 = (const f4v*)VT + bh * 4608;

    float m = -3.0e38f, l = 0.0f, s = 0.0f;
    float ac[33];
    #pragma unroll
    for (int a = 0; a < 33; ++a) ac[a] = 0.0f;

    for (int st = 0; st < 32; ++st) {
        const int k = t + 16 * st;
        f4v kr[9], vr[9];
        #pragma unroll
        for (int j = 0; j < 9; ++j) kr[j] = K4[j * 512 + k];
        #pragma unroll
        for (int j = 0; j < 9; ++j) vr[j] = V4[j * 512 + k];

        float p0 = 0.f, p1 = 0.f, p2 = 0.f, p3 = 0.f;
        #pragma unroll
        for (int j = 0; j < 9; ++j) {
            p0 = fmaf(qn[4 * j],     kr[j][0], p0);
            p1 = fmaf(qn[4 * j + 1], kr[j][1], p1);
            p2 = fmaf(qn[4 * j + 2], kr[j][2], p2);
            p3 = fmaf(qn[4 * j + 3], kr[j][3], p3);
        }
        const float a1 = (p0 + p1) + (p2 + p3);

        float r0 = 0.f, r1 = 0.f, r2 = 0.f, r3 = 0.f;
        #pragma unroll
        for (int j = 0; j < 9; ++j) {
            r0 = fmaf(qn[4 * j],     vr[j][0], r0);
            r1 = fmaf(qn[4 * j + 1], vr[j][1], r1);
            r2 = fmaf(qn[4 * j + 2], vr[j][2], r2);
            r3 = fmaf(qn[4 * j + 3], vr[j][3], r3);
        }
        const float a2 = (r0 + r1) + (r2 + r3);

        const float a1c = fminf(fmaxf(a1, 1.0f + EPSF), MAX_ACOSH_ARGF);
        const float d1  = fminf(facosh(a1c), MAX_DISTF);
        const float sN  = -d1 * d1;
        const float a2c = fminf(fmaxf(a2, 1.0f + EPSF), MAX_ACOSH_ARGF);
        const float d2  = facosh(a2c);

        if (sN > m) {                     // deferred rescale
            const float cr = __expf(m - sN);
            l *= cr; s *= cr;
            #pragma unroll
            for (int a = 0; a < 33; ++a) ac[a] *= cr;
            m = sN;
        }
        const float e = __expf(sN - m);
        l += e;
        const float w = e * d2;
        s = fmaf(w, a2c, s);
        #pragma unroll
        for (int a = 0; a < 33; ++a) ac[a] = fmaf(w, vr[a >> 2][a & 3], ac[a]);
    }

    // ---- 16-lane group merge ----
    float M = m;
    #pragma unroll
    for (int msk = 1; msk < 16; msk <<= 1) M = fmaxf(M, __shfl_xor(M, msk, 64));
    const float cl = __expf(m - M);
    float lw = l * cl, sw = s * cl;
    #pragma unroll
    for (int msk = 1; msk < 16; msk <<= 1) {
        lw += __shfl_xor(lw, msk, 64);
        sw += __shfl_xor(sw, msk, 64);
    }
    #pragma unroll
    for (int a = 0; a < 33; ++a) {
        float v = ac[a] * cl;
        #pragma unroll
        for (int msk = 1; msk < 16; msk <<= 1) v += __shfl_xor(v, msk, 64);
        ac[a] = v;
    }

    // ---- epilogue (redundant within group; lane t==0 stores) ----
    const float un_c  = sqrtf(TINYF);
    const float inv_un = (1.0f / lw) / un_c;
    // fold scalar Q-side accumulator; Qtrue = (qn[0], -qn[a>=1])
    ac[0] = fmaf(sw, qn[0], ac[0]) * inv_un;
    #pragma unroll
    for (int a = 1; a < 33; ++a) ac[a] = fmaf(-sw, qn[a], ac[a]) * inv_un;

    float mk = -ac[0] * ac[0];
    #pragma unroll
    for (int a = 1; a < 33; ++a) mk = fmaf(ac[a], ac[a], mk);
    const float snorm = sqrtf(fmaxf(mk, TINYF));
    const float fac   = fminf(snorm, 20.0f) / (snorm + 1e-9f);
    #pragma unroll
    for (int a = 0; a < 33; ++a) ac[a] *= fac;

    float mk2 = -ac[0] * ac[0];
    #pragma unroll
    for (int a = 1; a < 33; ++a) mk2 = fmaf(ac[a], ac[a], mk2);
    const float vn  = sqrtf(fmaxf(mk2, TINYF));
    const float ch  = coshf(vn);
    const float shr = sinhf(vn) / fmaxf(vn, TINYF);
    ac[0] = fmaf(ch, qn[0], shr * ac[0]);
    #pragma unroll
    for (int a = 1; a < 33; ++a) ac[a] = fmaf(-ch, qn[a], shr * ac[a]);  // y

    float xx = -ac[0] * ac[0];
    #pragma unroll
    for (int a = 1; a < 33; ++a) xx = fmaf(ac[a], ac[a], xx);
    const float scale = sqrtf(fmaxf(fabsf(xx), TINYF));

    const float Y0  = fabsf(ac[0] / scale);
    const float al3 = fminf(fmaxf(Y0, 1.0f + EPSF), MAX_ACOSH_ARGF);
    const float d3  = acoshf(al3);
    const float f3  = d3 / un_c;

    if (t == 0) {
        const int b = bh >> 3, h = bh & 7;
        float* zp = ZT + (b * 512 + qi) * 264 + h * 33;
        zp[0] = f3 * (Y0 + al3);
        const float fsc = f3 / scale;
        #pragma unroll
        for (int a = 1; a < 33; ++a) zp[a] = fsc * ac[a];
    }
}

// ---------------- Kernel 3: Z = Z_tan @ Wo + bo (LDS-free, reg-dbuf) ----------
__global__ __launch_bounds__(64) void out_kernel(
    const float* __restrict__ ZT, const float* __restrict__ Wo,
    const float* __restrict__ bo, float* __restrict__ out)
{
    const int lane = threadIdx.x;
    const int gw   = blockIdx.x;               // 0..1023
    const int mt   = gw >> 2;
    const int m0   = mt * 4;
    const int n0   = (gw & 3) * 128;
    const int c0   = n0 + lane * 2;
    const float* zb = ZT + m0 * 264;

    float acc[4][2];
    {
        const float b0 = bo[c0], b1 = bo[c0 + 1];
        #pragma unroll
        for (int r = 0; r < 4; ++r) { acc[r][0] = b0; acc[r][1] = b1; }
    }

    f4v aA[4][2], aB[4][2];
    f2v bA[8], bB[8];

#define LDA_O(BUF, KB)                                            \
    _Pragma("unroll") for (int r = 0; r < 4; ++r) {               \
        BUF[r][0] = *(const f4v*)(zb + r * 264 + (KB));           \
        BUF[r][1] = *(const f4v*)(zb + r * 264 + (KB) + 4);       \
    }
#define LDB_O(BUF, KB)                                            \
    _Pragma("unroll") for (int j = 0; j < 8; ++j)                 \
        BUF[j] = *(const f2v*)(Wo + ((KB) + j) * 512 + c0);
#define STEP_O(AB, BB)                                            \
    _Pragma("unroll") for (int j = 0; j < 8; ++j) {               \
        _Pragma("unroll") for (int r = 0; r < 4; ++r) {           \
            const float av = AB[r][j >> 2][j & 3];                \
            acc[r][0] = fmaf(av, BB[j][0], acc[r][0]);            \
            acc[r][1] = fmaf(av, BB[j][1], acc[r][1]);            \
        }                                                         \
    }

    LDA_O(aA, 0) LDB_O(bA, 0)
    for (int kb = 0; kb < 256; kb += 16) {     // 16 double-iters; tail below
        LDA_O(aB, kb + 8) LDB_O(bB, kb + 8)
        STEP_O(aA, bA)
        LDA_O(aA, kb + 16) LDB_O(bA, kb + 16)  // max KB=256 < 264, always valid
        STEP_O(aB, bB)
    }
    STEP_O(aA, bA)                              // k = 256..263

    #pragma unroll
    for (int r = 0; r < 4; ++r)
        *(f2v*)(out + (m0 + r) * 512 + c0) = f2v{acc[r][0], acc[r][1]};
}

extern "C" void kernel_launch(void* const* d_in, const int* in_sizes, int n_in,
                              void* d_out, int out_size, void* d_ws, size_t ws_size,
                              hipStream_t stream) {
    const float* x  = (const float*)d_in[0];
    const float* Wq = (const float*)d_in[1];
    const float* bq = (const float*)d_in[2];
    const float* Wk = (const float*)d_in[3];
    const float* bk = (const float*)d_in[4];
    const float* Wv = (const float*)d_in[5];
    const float* bv = (const float*)d_in[6];
    const float* Wo = (const float*)d_in[7];
    const float* bo = (const float*)d_in[8];
    float* out = (float*)d_out;
    float* ws  = (float*)d_ws;

    float* Qp  = ws;
    float* KT  = ws + QPSZ;
    float* VT  = ws + QPSZ + KTSZ;
    float* ZTp = ws + QPSZ + 2 * KTSZ;

    qkv_kernel<<<1536, 64, 0, stream>>>(x, Wq, bq, Wk, bk, Wv, bv, Qp, KT, VT);
    attn_kernel<<<512, 256, 0, stream>>>(Qp, KT, VT, ZTp);
    out_kernel<<<1024, 64, 0, stream>>>(ZTp, Wo, bo, out);
}